// Round 2
// baseline (143.332 us; speedup 1.0000x reference)
//
#include <hip/hip_runtime.h>

// GCN aggregator: out[r,:] = relu( (1/25 * sum_s F[idx[r,s],:]) @ W )
// r in [0, 32768), D_IN = D_OUT = 128, S = 25.
//
// Round 5b: L2-locality for the gather (compile-fixed: nontemporal builtins
// need ext_vector types, not HIP_vector_type).
//  G = bf16(F @ W) is stored COLUMN-CHUNKED: G[c][n][16] for c=0..7, i.e.
//  8 slices of [n_nodes][16 cols], 3.2 MB each — one slice fits a 4 MiB
//  per-XCD L2. The gather launches with chunk = blockIdx.x % 8; workgroup
//  dispatch round-robins XCDs, so XCD k only touches slice k => the 8.2x
//  avg node reuse becomes L2 hits instead of L3 traffic.
//  Kernel 1 transposes its C-fragments through LDS (reusing the B^T buffer)
//  so slice rows are node-major and stores stay 1 KB/inst contiguous.
//  Kernel 2: 2 lanes per output row, 16B per lane per sample; idx loads and
//  out stores are nontemporal to protect the hot slice in L2.

#define DEG 25
#define DIM 128

typedef __attribute__((ext_vector_type(8))) short short8;       // 8 bf16
typedef __attribute__((ext_vector_type(4))) float floatx4;      // 4 fp32
typedef __attribute__((ext_vector_type(4))) unsigned int uintx4; // 16 B

__device__ __forceinline__ unsigned short f2bf(float f) {
    // round-to-nearest-even fp32 -> bf16 (inputs finite)
    unsigned u = __float_as_uint(f);
    return (unsigned short)((u + 0x7fffu + ((u >> 16) & 1u)) >> 16);
}

// ---------------------------------------------------------------- GEMM ------
// G[c][n][16] = bf16( A[n,:] @ B[:,16c..16c+15] ), 128-row blocks, 4 waves,
// each wave: 32 rows x 128 cols via 16x16x32 bf16 MFMA.
#define BSTRIDE 136

__global__ __launch_bounds__(256, 2) void gemm_fw(
    const float* __restrict__ A,       // [M,128] fp32
    const float* __restrict__ B,       // [128,128] fp32
    unsigned short* __restrict__ G,    // [8][M][16] bf16 (column-chunked)
    int M)
{
    __shared__ unsigned short sBt[DIM * BSTRIDE];  // B^T [n][k], 34.8 KB

    const int tid = threadIdx.x;

    // ---- stage B transposed with fp32->bf16 (once per block)
    {
        const float4* B4 = (const float4*)B;
#pragma unroll
        for (int i = 0; i < 16; ++i) {
            const int linear = i * 256 + tid;   // 0..4095 float4s
            const int k  = linear >> 5;         // B row
            const int c4 = linear & 31;         // float4 within row
            const float4 v = B4[linear];
            const int n = c4 * 4;
            sBt[(n + 0) * BSTRIDE + k] = f2bf(v.x);
            sBt[(n + 1) * BSTRIDE + k] = f2bf(v.y);
            sBt[(n + 2) * BSTRIDE + k] = f2bf(v.z);
            sBt[(n + 3) * BSTRIDE + k] = f2bf(v.w);
        }
    }
    __syncthreads();

    const int wave = tid >> 6;
    const int lane = tid & 63;
    const int quad = lane >> 4;    // 0..3
    const int l16  = lane & 15;

    const int rw0 = blockIdx.x * 128 + wave * 32;   // wave's first row

    floatx4 acc[2][8];
#pragma unroll
    for (int mt = 0; mt < 2; ++mt)
#pragma unroll
        for (int nt = 0; nt < 8; ++nt)
            acc[mt][nt] = (floatx4){0.f, 0.f, 0.f, 0.f};

#pragma unroll
    for (int kt = 0; kt < 4; ++kt) {
        const int k0 = kt * 32;

        // A-frags: lane holds A[m=l16][k=k0+quad*8+j], j=0..7.
        short8 afrag[2];
#pragma unroll
        for (int mt = 0; mt < 2; ++mt) {
            int row = rw0 + mt * 16 + l16;
            if (row >= M) row = M - 1;          // tail clamp (stores guarded)
            const float* ap = A + (size_t)row * DIM + k0 + quad * 8;
            const float4 x = *(const float4*)ap;
            const float4 y = *(const float4*)(ap + 4);
            unsigned p0 = (unsigned)f2bf(x.x) | ((unsigned)f2bf(x.y) << 16);
            unsigned p1 = (unsigned)f2bf(x.z) | ((unsigned)f2bf(x.w) << 16);
            unsigned p2 = (unsigned)f2bf(y.x) | ((unsigned)f2bf(y.y) << 16);
            unsigned p3 = (unsigned)f2bf(y.z) | ((unsigned)f2bf(y.w) << 16);
            uintx4 packed = (uintx4){p0, p1, p2, p3};
            afrag[mt] = __builtin_bit_cast(short8, packed);
        }

        // B-frags from LDS: lane holds B[k=k0+quad*8+j][n=nt*16+l16]
#pragma unroll
        for (int nt = 0; nt < 8; ++nt) {
            const uintx4 u = *(const uintx4*)&sBt[(nt * 16 + l16) * BSTRIDE + k0 + quad * 8];
            const short8 bfrag = __builtin_bit_cast(short8, u);
#pragma unroll
            for (int mt = 0; mt < 2; ++mt)
                acc[mt][nt] = __builtin_amdgcn_mfma_f32_16x16x32_bf16(
                    afrag[mt], bfrag, acc[mt][nt], 0, 0, 0);
        }
    }

    // ---- transpose C tile through LDS (reuse sBt; all B reads are done).
    // C/D frag: elem r of lane = (row 16mt+quad*4+r, col 16nt+l16).
    // Wave w owns sBt[w*32*BSTRIDE ..]: a [32][BSTRIDE] bf16 tile, natural
    // (row, col) order.
    __syncthreads();   // everyone finished reading sBt
    {
        unsigned short* sT = sBt + wave * (32 * BSTRIDE);
#pragma unroll
        for (int mt = 0; mt < 2; ++mt)
#pragma unroll
            for (int nt = 0; nt < 8; ++nt)
#pragma unroll
                for (int r = 0; r < 4; ++r)
                    sT[(mt * 16 + quad * 4 + r) * BSTRIDE + nt * 16 + l16] =
                        f2bf(acc[mt][nt][r]);
    }
    __syncthreads();   // ordering of LDS writes vs cross-lane reads
    {
        const unsigned short* sT = sBt + wave * (32 * BSTRIDE);
        const int h    = lane & 1;      // which 16 B half of the 32 B row
        const int nrow = lane >> 1;     // 0..31: node within wave tile
        const int node = rw0 + nrow;
        if (node < M) {
            uintx4* G4 = (uintx4*)G;
#pragma unroll
            for (int c = 0; c < 8; ++c) {
                // lanes 0..63 cover 32 consecutive nodes' 32 B chunk rows:
                // one fully-contiguous 1 KB store per instruction.
                const uintx4 u = *(const uintx4*)&sT[nrow * BSTRIDE + c * 16 + h * 8];
                __builtin_nontemporal_store(u, &G4[((size_t)c * M + node) * 2 + h]);
            }
        }
    }
}

// ------------------------------------------------------- gather-mean-relu ---
// out[r, 16c..16c+15] = relu( 1/25 * sum_s Gc[idx[r,s], 0..15] ) for the
// block's chunk c = blockIdx.x % 8  (round-robin dispatch pins chunk<->XCD,
// so each XCD's L2 holds exactly its 3.2 MB slice).
// 2 lanes per row; lane owns the 16 B half-chunk at offset h*16.
#define ROWS_PB 128

__global__ __launch_bounds__(256, 4) void gather_mean_relu_c(
    const unsigned short* __restrict__ G,   // [8][n_nodes][16] bf16
    const int* __restrict__ idx,            // [n_rows,25]
    float* __restrict__ out,                // [n_rows,128] fp32
    int n_rows, int n_nodes)
{
    __shared__ int sIdx[ROWS_PB * DEG];     // 12.8 KB

    const int tid  = threadIdx.x;
    const int c    = blockIdx.x & 7;        // chunk == XCD (round-robin)
    const int rb   = blockIdx.x >> 3;
    const int row0 = rb * ROWS_PB;

    // stage this row-block's indices; nontemporal (streaming, protects slice)
    const int* ib = idx + (size_t)row0 * DEG;
    for (int i = tid; i < ROWS_PB * DEG; i += 256)
        sIdx[i] = __builtin_nontemporal_load(ib + i);
    __syncthreads();

    const int h = tid & 1;                  // 16 B half of the 32 B chunk row
    const int r = tid >> 1;                 // 0..127: row within block
    const uintx4* __restrict__ Gc =
        (const uintx4*)G + (size_t)c * n_nodes * 2 + h;

    float a0 = 0.f, a1 = 0.f, a2 = 0.f, a3 = 0.f;
    float a4 = 0.f, a5 = 0.f, a6 = 0.f, a7 = 0.f;
    const int* ip = &sIdx[r * DEG];

#pragma unroll
    for (int sb = 0; sb < 5; ++sb) {        // 5 batches of 5: bounded VGPRs,
        uintx4 v[5];                        // 5 loads in flight per thread
#pragma unroll
        for (int s = 0; s < 5; ++s)
            v[s] = Gc[(size_t)(unsigned)ip[sb * 5 + s] * 2];
#pragma unroll
        for (int s = 0; s < 5; ++s) {
            a0 += __uint_as_float(v[s].x << 16);
            a1 += __uint_as_float(v[s].x & 0xffff0000u);
            a2 += __uint_as_float(v[s].y << 16);
            a3 += __uint_as_float(v[s].y & 0xffff0000u);
            a4 += __uint_as_float(v[s].z << 16);
            a5 += __uint_as_float(v[s].z & 0xffff0000u);
            a6 += __uint_as_float(v[s].w << 16);
            a7 += __uint_as_float(v[s].w & 0xffff0000u);
        }
    }

    const float inv = 1.0f / 25.0f;
    const floatx4 o0 = (floatx4){fmaxf(a0 * inv, 0.f), fmaxf(a1 * inv, 0.f),
                                 fmaxf(a2 * inv, 0.f), fmaxf(a3 * inv, 0.f)};
    const floatx4 o1 = (floatx4){fmaxf(a4 * inv, 0.f), fmaxf(a5 * inv, 0.f),
                                 fmaxf(a6 * inv, 0.f), fmaxf(a7 * inv, 0.f)};
    // natural column order: 8 consecutive fp32 per lane, 64 B per row pair
    floatx4* op = (floatx4*)(out + (size_t)(row0 + r) * DIM + c * 16 + h * 8);
    __builtin_nontemporal_store(o0, op);
    __builtin_nontemporal_store(o1, op + 1);
}

// --------------------------------------------- fallback (round-2 kernel) ----
#define RPB 16
#define CG 32

__device__ __forceinline__ float4 relu4(float4 v) {
    return make_float4(fmaxf(v.x, 0.f), fmaxf(v.y, 0.f),
                       fmaxf(v.z, 0.f), fmaxf(v.w, 0.f));
}

__global__ __launch_bounds__(256, 4) void gcn_fused(
    const float* __restrict__ F, const int* __restrict__ idx,
    const float* __restrict__ W, float* __restrict__ out, int n_rows)
{
    __shared__ float4 sV[RPB * CG];
    __shared__ int    sIdx[RPB * DEG];

    const float4* F4 = (const float4*)F;
    const float4* W4 = (const float4*)W;
    float4* out4 = (float4*)out;

    const int tid = threadIdx.x;
    const int row0 = blockIdx.x * RPB;

    for (int i = tid; i < RPB * DEG; i += 256)
        sIdx[i] = idx[(size_t)row0 * DEG + i];
    __syncthreads();

    const int cg = tid & 31;
    const int rs = tid >> 5;

#pragma unroll
    for (int rr = 0; rr < 2; ++rr) {
        const int r = rs + rr * 8;
        int j[DEG];
#pragma unroll
        for (int s = 0; s < DEG; ++s) j[s] = sIdx[r * DEG + s];
        float4 acc = make_float4(0.f, 0.f, 0.f, 0.f);
#pragma unroll
        for (int s = 0; s < DEG; ++s) {
            float4 f = F4[(size_t)j[s] * CG + cg];
            acc.x += f.x; acc.y += f.y; acc.z += f.z; acc.w += f.w;
        }
        const float inv = 1.0f / 25.0f;
        acc.x *= inv; acc.y *= inv; acc.z *= inv; acc.w *= inv;
        sV[r * CG + cg] = acc;
    }
    __syncthreads();

    const float4* vA = &sV[rs * CG];
    const float4* vB = &sV[(rs + 8) * CG];
    float4 o0 = make_float4(0.f, 0.f, 0.f, 0.f);
    float4 o1 = make_float4(0.f, 0.f, 0.f, 0.f);
#pragma unroll 4
    for (int d4 = 0; d4 < CG; ++d4) {
        const float4 a = vA[d4];
        const float4 b = vB[d4];
        const float4 w0 = W4[(size_t)(4 * d4 + 0) * CG + cg];
        const float4 w1 = W4[(size_t)(4 * d4 + 1) * CG + cg];
        const float4 w2 = W4[(size_t)(4 * d4 + 2) * CG + cg];
        const float4 w3 = W4[(size_t)(4 * d4 + 3) * CG + cg];
        o0.x += a.x*w0.x + a.y*w1.x + a.z*w2.x + a.w*w3.x;
        o0.y += a.x*w0.y + a.y*w1.y + a.z*w2.y + a.w*w3.y;
        o0.z += a.x*w0.z + a.y*w1.z + a.z*w2.z + a.w*w3.z;
        o0.w += a.x*w0.w + a.y*w1.w + a.z*w2.w + a.w*w3.w;
        o1.x += b.x*w0.x + b.y*w1.x + b.z*w2.x + b.w*w3.x;
        o1.y += b.x*w0.y + b.y*w1.y + b.z*w2.y + b.w*w3.y;
        o1.z += b.x*w0.z + b.y*w1.z + b.z*w2.z + b.w*w3.z;
        o1.w += b.x*w0.w + b.y*w1.w + b.z*w2.w + b.w*w3.w;
    }
    out4[(size_t)(row0 + rs) * CG + cg]     = relu4(o0);
    out4[(size_t)(row0 + rs + 8) * CG + cg] = relu4(o1);
}

// ----------------------------------------------------------------------------
extern "C" void kernel_launch(void* const* d_in, const int* in_sizes, int n_in,
                              void* d_out, int out_size, void* d_ws, size_t ws_size,
                              hipStream_t stream) {
    const float* F   = (const float*)d_in[0];   // features [100000,128] fp32
    const int*   idx = (const int*)d_in[1];     // sample_res [8,4096,25] int32
    const float* W   = (const float*)d_in[2];   // weights [128,128] fp32
    float* out = (float*)d_out;                 // [8,4096,128] fp32

    const int n_nodes = in_sizes[0] / DIM;      // 100000
    const int n_rows  = in_sizes[1] / DEG;      // 32768

    const size_t need = (size_t)n_nodes * DIM * sizeof(unsigned short);
    if (ws_size >= need && (n_rows & (ROWS_PB - 1)) == 0) {
        unsigned short* G = (unsigned short*)d_ws;
        gemm_fw<<<(n_nodes + 127) / 128, 256, 0, stream>>>(F, W, G, n_nodes);
        gather_mean_relu_c<<<(n_rows / ROWS_PB) * 8, 256, 0, stream>>>(
            G, idx, out, n_rows, n_nodes);
    } else {
        gcn_fused<<<n_rows / RPB, 256, 0, stream>>>(F, idx, W, out, n_rows);
    }
}